// Round 6
// baseline (189.325 us; speedup 1.0000x reference)
//
#include <hip/hip_runtime.h>

// 2-layer GAT forward, N nodes, K=16 neighbors (row-sorted, exactly 16/dst),
// feats 128 -> 64 -> 64, fp32 in/out.
//
// K1: h1 = x @ W1 (fp16 MFMA, A-single/W-dual split) + scores s1a,s2a
// K2 (FUSED): attn over h1 -> xm rows (LDS only, never global) -> MFMA @ W2
//             -> h2 + scores s1b,s2b
// K3: attn over h2 -> fp32 out
// All intermediates fp16 (halves gather traffic); fp32 accumulation throughout.

typedef __attribute__((ext_vector_type(8))) _Float16 f16x8;
typedef __attribute__((ext_vector_type(4))) _Float16 f16x4;
typedef __attribute__((ext_vector_type(4))) float floatx4;

__device__ inline float ubitf(unsigned u) { union { unsigned u; float f; } v; v.u = u; return v.f; }
__device__ inline unsigned fbitu(float f) { union { float f; unsigned u; } v; v.f = f; return v.u; }

// ---------------- K1: h1 = X(fp32) @ W1 (dual-fp16 MFMA) + scores ----------
// 256 thr = 4 waves, 48 rows/wave. W-frag f=(kt*4+nt)*64+lane holds
// B[k=kt*32+(lane>>4)*8+j][c=nt*16+(lane&15)].
template<int KD>
__global__ __launch_bounds__(256, 2) void gemm_score_f16(
    const float* __restrict__ X, const float* __restrict__ W,
    const float* __restrict__ av, _Float16* __restrict__ H,
    float* __restrict__ s1, float* __restrict__ s2, int n)
{
    constexpr int NKT = KD / 32;
    constexpr int NF = NKT * 4 * 64;
    __shared__ f16x8 Bhi[NF];
    __shared__ f16x8 Blo[NF];
    const int tid = threadIdx.x;

    for (int f = tid; f < NF; f += 256) {
        const int ln = f & 63, ntk = f >> 6;
        const int kt = ntk >> 2, nt = ntk & 3;
        const int kbase = kt * 32 + (ln >> 4) * 8;
        const int ccol = nt * 16 + (ln & 15);
        f16x8 hh, ll;
#pragma unroll
        for (int j = 0; j < 8; j++) {
            const float w = W[(kbase + j) * 64 + ccol];
            const _Float16 wh = (_Float16)w;
            hh[j] = wh;
            ll[j] = (_Float16)(w - (float)wh);
        }
        Bhi[f] = hh; Blo[f] = ll;
    }
    __syncthreads();

    const int wave = tid >> 6, lane = tid & 63;
    const int quad = lane >> 4, l15 = lane & 15;
    const int r0 = blockIdx.x * 192 + wave * 48;

    float a1c[4], a2c[4];
#pragma unroll
    for (int nt = 0; nt < 4; nt++) {
        a1c[nt] = av[nt * 16 + l15];
        a2c[nt] = av[64 + nt * 16 + l15];
    }

    // prefetch all raw X for the wave's 48 rows
    float4 raw[NKT][3][2];
#pragma unroll
    for (int rb = 0; rb < 3; rb++) {
        int ra = r0 + rb * 16 + l15; if (ra > n - 1) ra = n - 1;
        const float* xp = &X[(size_t)ra * KD + quad * 8];
#pragma unroll
        for (int kt = 0; kt < NKT; kt++) {
            raw[kt][rb][0] = *(const float4*)(xp + kt * 32);
            raw[kt][rb][1] = *(const float4*)(xp + kt * 32 + 4);
        }
    }
    f16x8 A[NKT][3];
#pragma unroll
    for (int kt = 0; kt < NKT; kt++)
#pragma unroll
        for (int rb = 0; rb < 3; rb++) {
            f16x8 a;
            a[0] = (_Float16)raw[kt][rb][0].x; a[1] = (_Float16)raw[kt][rb][0].y;
            a[2] = (_Float16)raw[kt][rb][0].z; a[3] = (_Float16)raw[kt][rb][0].w;
            a[4] = (_Float16)raw[kt][rb][1].x; a[5] = (_Float16)raw[kt][rb][1].y;
            a[6] = (_Float16)raw[kt][rb][1].z; a[7] = (_Float16)raw[kt][rb][1].w;
            A[kt][rb] = a;
        }

    floatx4 acc[4][3];
#pragma unroll
    for (int nt = 0; nt < 4; nt++)
#pragma unroll
        for (int rb = 0; rb < 3; rb++) acc[nt][rb] = (floatx4){0, 0, 0, 0};

#pragma unroll
    for (int kt = 0; kt < NKT; kt++)
#pragma unroll
        for (int nt = 0; nt < 4; nt++) {
            const f16x8 bh = Bhi[(kt * 4 + nt) * 64 + lane];
            const f16x8 bl = Blo[(kt * 4 + nt) * 64 + lane];
#pragma unroll
            for (int rb = 0; rb < 3; rb++) {
                acc[nt][rb] = __builtin_amdgcn_mfma_f32_16x16x32_f16(A[kt][rb], bh, acc[nt][rb], 0, 0, 0);
                acc[nt][rb] = __builtin_amdgcn_mfma_f32_16x16x32_f16(A[kt][rb], bl, acc[nt][rb], 0, 0, 0);
            }
        }

    // epilogue: C layout col=nt*16+l15, row=quad*4+reg
#pragma unroll
    for (int rb = 0; rb < 3; rb++) {
        float p1[4] = {0, 0, 0, 0}, p2[4] = {0, 0, 0, 0};
#pragma unroll
        for (int nt = 0; nt < 4; nt++)
#pragma unroll
            for (int reg = 0; reg < 4; reg++) {
                const int r = r0 + rb * 16 + quad * 4 + reg;
                if (r < n) H[(size_t)r * 64 + nt * 16 + l15] = (_Float16)acc[nt][rb][reg];
                p1[reg] = fmaf(acc[nt][rb][reg], a1c[nt], p1[reg]);
                p2[reg] = fmaf(acc[nt][rb][reg], a2c[nt], p2[reg]);
            }
#pragma unroll
        for (int m = 1; m < 16; m <<= 1)
#pragma unroll
            for (int reg = 0; reg < 4; reg++) {
                p1[reg] += __shfl_xor(p1[reg], m, 64);
                p2[reg] += __shfl_xor(p2[reg], m, 64);
            }
        if (l15 == 0)
#pragma unroll
            for (int reg = 0; reg < 4; reg++) {
                const int r = r0 + rb * 16 + quad * 4 + reg;
                if (r < n) { s1[r] = p1[reg]; s2[r] = p2[reg]; }
            }
    }
}

// ---------------- K2: FUSED attn(h1)->xm(LDS)->gemm(W2)->h2 + scores -------
// 256 thr = 4 waves, 48 rows/wave. Attention: 6 chunks of 8 nodes/wave,
// lane = g*8+j (node g, lane-within-node j); lane owns feats j*8..j*8+7.
__global__ __launch_bounds__(256, 2) void attn_gemm_fused(
    const _Float16* __restrict__ H1, const float* __restrict__ s1a,
    const float* __restrict__ s2a, const int* __restrict__ col,
    const float* __restrict__ bias1, const float* __restrict__ W2,
    const float* __restrict__ av, _Float16* __restrict__ H2,
    float* __restrict__ s1b, float* __restrict__ s2b, int n)
{
    constexpr int NKT = 2;                 // K = 64
    constexpr int NF = NKT * 4 * 64;       // 512 fragments
    constexpr int XST = 72;                // padded LDS row stride (fp16): 2-way read conflicts only
    __shared__ f16x8 Bhi[NF];
    __shared__ f16x8 Blo[NF];
    __shared__ _Float16 Xs[4][48 * XST];   // 4 waves x 48 rows
    const int tid = threadIdx.x;

    for (int f = tid; f < NF; f += 256) {
        const int ln = f & 63, ntk = f >> 6;
        const int kt = ntk >> 2, nt = ntk & 3;
        const int kbase = kt * 32 + (ln >> 4) * 8;
        const int ccol = nt * 16 + (ln & 15);
        f16x8 hh, ll;
#pragma unroll
        for (int j = 0; j < 8; j++) {
            const float w = W2[(kbase + j) * 64 + ccol];
            const _Float16 wh = (_Float16)w;
            hh[j] = wh;
            ll[j] = (_Float16)(w - (float)wh);
        }
        Bhi[f] = hh; Blo[f] = ll;
    }
    __syncthreads();     // last barrier — safe for partial waves below

    const int wave = tid >> 6, lane = tid & 63;
    const int g = (lane >> 3) & 7, j = lane & 7;
    const int r0 = blockIdx.x * 192 + wave * 48;
    _Float16* xw = Xs[wave];

    float bb[8];
    *(float4*)&bb[0] = *(const float4*)&bias1[j * 8];
    *(float4*)&bb[4] = *(const float4*)&bias1[j * 8 + 4];

    // ---- attention phase: level-1 loads for all 6 chunks up front (MLP) ----
    int c0v[6], c1v[6]; float s1v[6];
#pragma unroll
    for (int ch = 0; ch < 6; ch++) {
        int dc = r0 + ch * 8 + g; if (dc > n - 1) dc = n - 1;
        c0v[ch] = col[dc * 16 + j];
        c1v[ch] = col[dc * 16 + 8 + j];
        s1v[ch] = s1a[dc];
    }
    float e0v[6], e1v[6];
#pragma unroll
    for (int ch = 0; ch < 6; ch++) {
        e0v[ch] = s1v[ch] + s2a[c0v[ch]];
        e1v[ch] = s1v[ch] + s2a[c1v[ch]];
    }
    const int bb4 = (lane & 56) << 2;      // bpermute group-base byte index
#pragma unroll
    for (int ch = 0; ch < 6; ch++) {
        float e0 = e0v[ch]; e0 = (e0 > 0.0f) ? e0 : 0.2f * e0;
        float e1 = e1v[ch]; e1 = (e1 > 0.0f) ? e1 : 0.2f * e1;
        float m = fmaxf(e0, e1);
        m = fmaxf(m, __shfl_xor(m, 1, 64));
        m = fmaxf(m, __shfl_xor(m, 2, 64));
        m = fmaxf(m, __shfl_xor(m, 4, 64));
        const float p0 = __expf(e0 - m), p1 = __expf(e1 - m);
        float s = p0 + p1;
        s += __shfl_xor(s, 1, 64); s += __shfl_xor(s, 2, 64); s += __shfl_xor(s, 4, 64);
        const float inv = 1.0f / s;
        const float att0 = p0 * inv, att1 = p1 * inv;

        int srck[16]; float attk[16];
#pragma unroll
        for (int k = 0; k < 8; k++) {
            srck[k]     = __builtin_amdgcn_ds_bpermute(bb4 + 4 * k, c0v[ch]);
            srck[k + 8] = __builtin_amdgcn_ds_bpermute(bb4 + 4 * k, c1v[ch]);
            attk[k]     = ubitf((unsigned)__builtin_amdgcn_ds_bpermute(bb4 + 4 * k, (int)fbitu(att0)));
            attk[k + 8] = ubitf((unsigned)__builtin_amdgcn_ds_bpermute(bb4 + 4 * k, (int)fbitu(att1)));
        }
        f16x8 hv[16];
#pragma unroll
        for (int k = 0; k < 16; k++)
            hv[k] = *(const f16x8*)&H1[(size_t)srck[k] * 64 + j * 8];   // 1 KB/wave/instr
        float acc[8] = {0, 0, 0, 0, 0, 0, 0, 0};
#pragma unroll
        for (int k = 0; k < 16; k++)
#pragma unroll
            for (int t = 0; t < 8; t++)
                acc[t] = fmaf(attk[k], (float)hv[k][t], acc[t]);    // v_fma_mix
        f16x8 xv;
#pragma unroll
        for (int t = 0; t < 8; t++)
            xv[t] = (_Float16)fmaxf(acc[t] + bb[t], 0.0f);          // relu(agg+b1)
        *(f16x8*)&xw[(ch * 8 + g) * XST + j * 8] = xv;              // ds_write_b128
    }

    // ---- gemm phase: A-frags straight from LDS (no global xm) ----
    const int quad = lane >> 4, l15 = lane & 15;
    float a1c[4], a2c[4];
#pragma unroll
    for (int nt = 0; nt < 4; nt++) {
        a1c[nt] = av[nt * 16 + l15];
        a2c[nt] = av[64 + nt * 16 + l15];
    }
    floatx4 acc2[4][3];
#pragma unroll
    for (int nt = 0; nt < 4; nt++)
#pragma unroll
        for (int rb = 0; rb < 3; rb++) acc2[nt][rb] = (floatx4){0, 0, 0, 0};

#pragma unroll
    for (int kt = 0; kt < NKT; kt++) {
        f16x8 A[3];
#pragma unroll
        for (int rb = 0; rb < 3; rb++)
            A[rb] = *(const f16x8*)&xw[(rb * 16 + l15) * XST + kt * 32 + quad * 8];
#pragma unroll
        for (int nt = 0; nt < 4; nt++) {
            const f16x8 bh = Bhi[(kt * 4 + nt) * 64 + lane];
            const f16x8 bl = Blo[(kt * 4 + nt) * 64 + lane];
#pragma unroll
            for (int rb = 0; rb < 3; rb++) {
                acc2[nt][rb] = __builtin_amdgcn_mfma_f32_16x16x32_f16(A[rb], bh, acc2[nt][rb], 0, 0, 0);
                acc2[nt][rb] = __builtin_amdgcn_mfma_f32_16x16x32_f16(A[rb], bl, acc2[nt][rb], 0, 0, 0);
            }
        }
    }

#pragma unroll
    for (int rb = 0; rb < 3; rb++) {
        float p1[4] = {0, 0, 0, 0}, p2[4] = {0, 0, 0, 0};
#pragma unroll
        for (int nt = 0; nt < 4; nt++)
#pragma unroll
            for (int reg = 0; reg < 4; reg++) {
                const int r = r0 + rb * 16 + quad * 4 + reg;
                if (r < n) H2[(size_t)r * 64 + nt * 16 + l15] = (_Float16)acc2[nt][rb][reg];
                p1[reg] = fmaf(acc2[nt][rb][reg], a1c[nt], p1[reg]);
                p2[reg] = fmaf(acc2[nt][rb][reg], a2c[nt], p2[reg]);
            }
#pragma unroll
        for (int m = 1; m < 16; m <<= 1)
#pragma unroll
            for (int reg = 0; reg < 4; reg++) {
                p1[reg] += __shfl_xor(p1[reg], m, 64);
                p2[reg] += __shfl_xor(p2[reg], m, 64);
            }
        if (l15 == 0)
#pragma unroll
            for (int reg = 0; reg < 4; reg++) {
                const int r = r0 + rb * 16 + quad * 4 + reg;
                if (r < n) { s1b[r] = p1[reg]; s2b[r] = p2[reg]; }
            }
    }
}

// ---------------- K3: final attention, 8 nodes/wave, fp32 out --------------
__global__ __launch_bounds__(512) void attn_final(
    const _Float16* __restrict__ H, const float* __restrict__ s1,
    const float* __restrict__ s2, const int* __restrict__ col,
    const float* __restrict__ bias, float* __restrict__ out, int n)
{
    const int lane = threadIdx.x & 63;
    const int wv = threadIdx.x >> 6;                 // 0..7
    const int g = (lane >> 3) & 7, j = lane & 7;
    const int dst = blockIdx.x * 64 + wv * 8 + g;
    const int dc = (dst > n - 1) ? (n - 1) : dst;

    const int c0 = col[dc * 16 + j];
    const int c1 = col[dc * 16 + 8 + j];
    const float s1d = s1[dc];
    float e0 = s1d + s2[c0];
    float e1 = s1d + s2[c1];
    e0 = (e0 > 0.0f) ? e0 : 0.2f * e0;
    e1 = (e1 > 0.0f) ? e1 : 0.2f * e1;
    float m = fmaxf(e0, e1);
    m = fmaxf(m, __shfl_xor(m, 1, 64));
    m = fmaxf(m, __shfl_xor(m, 2, 64));
    m = fmaxf(m, __shfl_xor(m, 4, 64));
    const float p0 = __expf(e0 - m), p1 = __expf(e1 - m);
    float s = p0 + p1;
    s += __shfl_xor(s, 1, 64); s += __shfl_xor(s, 2, 64); s += __shfl_xor(s, 4, 64);
    const float inv = 1.0f / s;
    const float att0 = p0 * inv, att1 = p1 * inv;

    const int bb4 = (lane & 56) << 2;
    int srck[16]; float attk[16];
#pragma unroll
    for (int k = 0; k < 8; k++) {
        srck[k]     = __builtin_amdgcn_ds_bpermute(bb4 + 4 * k, c0);
        srck[k + 8] = __builtin_amdgcn_ds_bpermute(bb4 + 4 * k, c1);
        attk[k]     = ubitf((unsigned)__builtin_amdgcn_ds_bpermute(bb4 + 4 * k, (int)fbitu(att0)));
        attk[k + 8] = ubitf((unsigned)__builtin_amdgcn_ds_bpermute(bb4 + 4 * k, (int)fbitu(att1)));
    }
    f16x8 hv[16];
#pragma unroll
    for (int k = 0; k < 16; k++)
        hv[k] = *(const f16x8*)&H[(size_t)srck[k] * 64 + j * 8];
    float acc[8] = {0, 0, 0, 0, 0, 0, 0, 0};
#pragma unroll
    for (int k = 0; k < 16; k++)
#pragma unroll
        for (int t = 0; t < 8; t++)
            acc[t] = fmaf(attk[k], (float)hv[k][t], acc[t]);

    if (dst < n) {
        float4 b0 = *(const float4*)&bias[j * 8];
        float4 b1v = *(const float4*)&bias[j * 8 + 4];
        float4 o0, o1;
        o0.x = fmaxf(acc[0] + b0.x, 0.0f); o0.y = fmaxf(acc[1] + b0.y, 0.0f);
        o0.z = fmaxf(acc[2] + b0.z, 0.0f); o0.w = fmaxf(acc[3] + b0.w, 0.0f);
        o1.x = fmaxf(acc[4] + b1v.x, 0.0f); o1.y = fmaxf(acc[5] + b1v.y, 0.0f);
        o1.z = fmaxf(acc[6] + b1v.z, 0.0f); o1.w = fmaxf(acc[7] + b1v.w, 0.0f);
        *(float4*)&out[(size_t)dst * 64 + j * 8] = o0;
        *(float4*)&out[(size_t)dst * 64 + j * 8 + 4] = o1;
    }
}

extern "C" void kernel_launch(void* const* d_in, const int* in_sizes, int n_in,
                              void* d_out, int out_size, void* d_ws, size_t ws_size,
                              hipStream_t stream)
{
    const float* x        = (const float*)d_in[0];
    const int*   edge_col = (const int*)  d_in[2];
    const float* W1       = (const float*)d_in[3];
    const float* a1       = (const float*)d_in[4];
    const float* b1       = (const float*)d_in[5];
    const float* W2       = (const float*)d_in[6];
    const float* a2       = (const float*)d_in[7];
    const float* b2       = (const float*)d_in[8];
    const int n = in_sizes[0] / 128;     // 100000

    _Float16* h1 = (_Float16*)d_ws;                  // n*64 fp16
    _Float16* h2 = h1 + (size_t)n * 64;              // n*64 fp16
    float* s1a = (float*)(h2 + (size_t)n * 64);      // n
    float* s2a = s1a + n;                            // n
    float* s1b = s2a + n;                            // n
    float* s2b = s1b + n;                            // n

    const int gemm_blocks = (n + 191) / 192;         // 521
    const int fin_blocks  = (n + 63) / 64;           // 1563

    gemm_score_f16<128><<<gemm_blocks, 256, 0, stream>>>(x, W1, a1, h1, s1a, s2a, n);
    attn_gemm_fused<<<gemm_blocks, 256, 0, stream>>>(h1, s1a, s2a, edge_col, b1,
                                                     W2, a2, h2, s1b, s2b, n);
    attn_final<<<fin_blocks, 512, 0, stream>>>(h2, s1b, s2b, edge_col, b2, (float*)d_out, n);
}